// Round 1
// baseline (1461.557 us; speedup 1.0000x reference)
//
#include <hip/hip_runtime.h>
#include <stdint.h>
#include <stddef.h>

// Problem constants (QuantizedLinear: y = x @ (q*scale)^T)
#define M_DIM 8192   // 4*2048 rows of x
#define N_DIM 11008  // output channels
#define K_DIM 4096   // in features

typedef __attribute__((ext_vector_type(8))) __bf16 bf16x8;
typedef __attribute__((ext_vector_type(4))) float f32x4;

typedef const __attribute__((address_space(1))) void gvoid;
typedef __attribute__((address_space(3))) void lvoid;

__device__ __forceinline__ void async16(const void* g, void* l) {
  // global -> LDS direct copy, 16B/lane; LDS dest is wave-uniform base + lane*16
  __builtin_amdgcn_global_load_lds((gvoid*)g, (lvoid*)l, 16, 0, 0);
}

// round-to-nearest-even f32 -> bf16 (no NaN handling needed: inputs are finite)
__device__ __forceinline__ unsigned short f2bf(float f) {
  unsigned u = __float_as_uint(f);
  u += 0x7fffu + ((u >> 16) & 1u);
  return (unsigned short)(u >> 16);
}

// ---------------- conversion passes (memory-bound) ----------------

__global__ __launch_bounds__(256) void cvt_x_kernel(const float* __restrict__ x,
                                                    unsigned short* __restrict__ xw) {
  size_t i = ((size_t)blockIdx.x * 256 + threadIdx.x) * 4;
  float4 v = *(const float4*)(x + i);
  ushort4 o;
  o.x = f2bf(v.x); o.y = f2bf(v.y); o.z = f2bf(v.z); o.w = f2bf(v.w);
  *(ushort4*)(xw + i) = o;
}

__global__ __launch_bounds__(256) void cvt_w_kernel(const int* __restrict__ wq,
                                                    unsigned short* __restrict__ ww) {
  size_t i = ((size_t)blockIdx.x * 256 + threadIdx.x) * 4;
  int4 v = *(const int4*)(wq + i);
  ushort4 o;  // int values in [0,127) are exact in bf16
  o.x = f2bf((float)v.x); o.y = f2bf((float)v.y);
  o.z = f2bf((float)v.z); o.w = f2bf((float)v.w);
  *(ushort4*)(ww + i) = o;
}

// ---------------- main GEMM: 128x128 tile, BK=32, 4 waves of 64x64 ----------------
// A = x (M x K, K-contig), B = W (N x K, K-contig)  ->  C[m][n] = scale[n]*sum_k A*B

__global__ __launch_bounds__(256) void gemm_bf16(const unsigned short* __restrict__ xw,
                                                 const unsigned short* __restrict__ ww,
                                                 const float* __restrict__ scale,
                                                 float* __restrict__ out) {
  __shared__ unsigned short As[128 * 32];  // [row][32] dense, 8 KB
  __shared__ unsigned short Bs[128 * 32];

  const int tid = threadIdx.x;
  const int w = tid >> 6;   // wave 0..3
  const int l = tid & 63;   // lane
  const int n0 = blockIdx.x * 128;
  const int m0 = blockIdx.y * 128;

  // staging: lane l of wave w covers row w*16 + l/4 (per 64-row half), col chunk (l&3)*8
  const int srow = w * 16 + (l >> 2);
  const int scol = (l & 3) * 8;
  const unsigned short* ga = xw + (size_t)(m0 + srow) * K_DIM + scol;
  const unsigned short* gb = ww + (size_t)(n0 + srow) * K_DIM + scol;
  unsigned short* lA0 = &As[w * 512];          // byte w*1024; HW adds lane*16
  unsigned short* lA1 = &As[2048 + w * 512];   // rows 64..127
  unsigned short* lB0 = &Bs[w * 512];
  unsigned short* lB1 = &Bs[2048 + w * 512];

  // compute: wave (wm,wn) owns 64x64 quadrant; 4x4 grid of 16x16x32 MFMAs
  const int wm = w >> 1, wn = w & 1;
  const int fm = l & 15;   // A: m index / B: n index
  const int q = l >> 4;    // k-quad: k = q*8 + j
  const unsigned short* pA = &As[(wm * 64 + fm) * 32 + q * 8];
  const unsigned short* pB = &Bs[(wn * 64 + fm) * 32 + q * 8];

  f32x4 acc[4][4];
#pragma unroll
  for (int i = 0; i < 4; i++)
#pragma unroll
    for (int j = 0; j < 4; j++) acc[i][j] = {0.f, 0.f, 0.f, 0.f};

  for (int kk = 0; kk < K_DIM; kk += 32) {
    __syncthreads();  // previous tile's ds_reads done before overwrite
    async16(ga + kk, lA0);
    async16(ga + kk + (size_t)64 * K_DIM, lA1);
    async16(gb + kk, lB0);
    async16(gb + kk + (size_t)64 * K_DIM, lB1);
    __syncthreads();  // compiler emits s_waitcnt vmcnt(0) before s_barrier

    bf16x8 af[4], bf[4];
#pragma unroll
    for (int i = 0; i < 4; i++) af[i] = *(const bf16x8*)(pA + i * 16 * 32);
#pragma unroll
    for (int j = 0; j < 4; j++) bf[j] = *(const bf16x8*)(pB + j * 16 * 32);
#pragma unroll
    for (int i = 0; i < 4; i++)
#pragma unroll
      for (int j = 0; j < 4; j++)
        acc[i][j] = __builtin_amdgcn_mfma_f32_16x16x32_bf16(af[i], bf[j], acc[i][j], 0, 0, 0);
  }

  // epilogue: C/D layout col=lane&15, row=(lane>>4)*4+reg; fuse per-channel scale
  float sc[4];
  const int baseN = n0 + wn * 64 + fm;
#pragma unroll
  for (int j = 0; j < 4; j++) sc[j] = scale[baseN + j * 16];
#pragma unroll
  for (int i = 0; i < 4; i++) {
#pragma unroll
    for (int r = 0; r < 4; r++) {
      size_t row = (size_t)(m0 + wm * 64 + i * 16 + q * 4 + r);
      float* po = out + row * N_DIM + baseN;
#pragma unroll
      for (int j = 0; j < 4; j++) po[j * 16] = acc[i][j][r] * sc[j];
    }
  }
}

// ---------------- fallback: fused conversion GEMM (no workspace) ----------------

__global__ __launch_bounds__(256) void gemm_fused(const float* __restrict__ x,
                                                  const int* __restrict__ wq,
                                                  const float* __restrict__ scale,
                                                  float* __restrict__ out) {
  __shared__ unsigned short As[128 * 32];
  __shared__ unsigned short Bs[128 * 32];

  const int tid = threadIdx.x;
  const int w = tid >> 6, l = tid & 63;
  const int n0 = blockIdx.x * 128;
  const int m0 = blockIdx.y * 128;

  const int srow = tid >> 2;        // 0..63
  const int scol = (tid & 3) * 8;   // 0,8,16,24

  const int wm = w >> 1, wn = w & 1;
  const int fm = l & 15, q = l >> 4;
  const unsigned short* pA = &As[(wm * 64 + fm) * 32 + q * 8];
  const unsigned short* pB = &Bs[(wn * 64 + fm) * 32 + q * 8];

  f32x4 acc[4][4];
#pragma unroll
  for (int i = 0; i < 4; i++)
#pragma unroll
    for (int j = 0; j < 4; j++) acc[i][j] = {0.f, 0.f, 0.f, 0.f};

  for (int kk = 0; kk < K_DIM; kk += 32) {
    __syncthreads();
#pragma unroll
    for (int h = 0; h < 2; h++) {
      int row = h * 64 + srow;
      const float* pa = x + (size_t)(m0 + row) * K_DIM + kk + scol;
      float4 a0 = *(const float4*)pa;
      float4 a1 = *(const float4*)(pa + 4);
      union { unsigned short us[8]; bf16x8 v; } ua;
      ua.us[0] = f2bf(a0.x); ua.us[1] = f2bf(a0.y); ua.us[2] = f2bf(a0.z); ua.us[3] = f2bf(a0.w);
      ua.us[4] = f2bf(a1.x); ua.us[5] = f2bf(a1.y); ua.us[6] = f2bf(a1.z); ua.us[7] = f2bf(a1.w);
      *(bf16x8*)&As[row * 32 + scol] = ua.v;

      const int* pb = wq + (size_t)(n0 + row) * K_DIM + kk + scol;
      int4 b0 = *(const int4*)pb;
      int4 b1 = *(const int4*)(pb + 4);
      union { unsigned short us[8]; bf16x8 v; } ub;
      ub.us[0] = f2bf((float)b0.x); ub.us[1] = f2bf((float)b0.y);
      ub.us[2] = f2bf((float)b0.z); ub.us[3] = f2bf((float)b0.w);
      ub.us[4] = f2bf((float)b1.x); ub.us[5] = f2bf((float)b1.y);
      ub.us[6] = f2bf((float)b1.z); ub.us[7] = f2bf((float)b1.w);
      *(bf16x8*)&Bs[row * 32 + scol] = ub.v;
    }
    __syncthreads();

    bf16x8 af[4], bf[4];
#pragma unroll
    for (int i = 0; i < 4; i++) af[i] = *(const bf16x8*)(pA + i * 16 * 32);
#pragma unroll
    for (int j = 0; j < 4; j++) bf[j] = *(const bf16x8*)(pB + j * 16 * 32);
#pragma unroll
    for (int i = 0; i < 4; i++)
#pragma unroll
      for (int j = 0; j < 4; j++)
        acc[i][j] = __builtin_amdgcn_mfma_f32_16x16x32_bf16(af[i], bf[j], acc[i][j], 0, 0, 0);
  }

  float sc[4];
  const int baseN = n0 + wn * 64 + fm;
#pragma unroll
  for (int j = 0; j < 4; j++) sc[j] = scale[baseN + j * 16];
#pragma unroll
  for (int i = 0; i < 4; i++) {
#pragma unroll
    for (int r = 0; r < 4; r++) {
      size_t row = (size_t)(m0 + wm * 64 + i * 16 + q * 4 + r);
      float* po = out + row * N_DIM + baseN;
#pragma unroll
      for (int j = 0; j < 4; j++) po[j * 16] = acc[i][j][r] * sc[j];
    }
  }
}

extern "C" void kernel_launch(void* const* d_in, const int* in_sizes, int n_in,
                              void* d_out, int out_size, void* d_ws, size_t ws_size,
                              hipStream_t stream) {
  const float* x = (const float*)d_in[0];
  const int* wq = (const int*)d_in[1];
  const float* sc = (const float*)d_in[2];
  float* out = (float*)d_out;

  const size_t xE = (size_t)M_DIM * K_DIM;  // 33,554,432
  const size_t wE = (size_t)N_DIM * K_DIM;  // 45,088,768
  const size_t need = (xE + wE) * sizeof(unsigned short);  // ~150 MB

  dim3 grid(N_DIM / 128, M_DIM / 128);  // 86 x 64

  if (ws_size >= need) {
    unsigned short* xw = (unsigned short*)d_ws;
    unsigned short* ww = xw + xE;
    cvt_x_kernel<<<(unsigned)(xE / 1024), 256, 0, stream>>>(x, xw);
    cvt_w_kernel<<<(unsigned)(wE / 1024), 256, 0, stream>>>(wq, ww);
    gemm_bf16<<<grid, 256, 0, stream>>>(xw, ww, sc, out);
  } else {
    gemm_fused<<<grid, 256, 0, stream>>>(x, wq, sc, out);
  }
}